// Round 1
// baseline (377.281 us; speedup 1.0000x reference)
//
#include <hip/hip_runtime.h>
#include <stdint.h>
#include <stddef.h>

// ---------------------------------------------------------------------------
// Attention: out = softmax(Q K^T) * sqrt(512) @ V,  Q=x Wq+bq etc.
// B=8, N=2048, D=DK=DV=512.  fp32 I/O.
// Strategy: bf16 hi/lo split MFMA for the score path (x,W,Q,K), plain bf16
// for the value path (P,V). 4 kernels: proj GEMM, QK^T GEMM, row softmax,
// PV GEMM. ws layout (bytes):
//   Qhi 0, Qlo 16M, Khi 32M, Klo 48M, Vt 64M (each 16,777,216 B)
//   S   at 83,886,080 (134,217,728 B fp32; P bf16 overlaid in-place per row)
//   linv at 218,103,808 (65,536 B)
// total 218,169,344 B required in d_ws.
// ---------------------------------------------------------------------------

typedef __bf16 bf16_t;
typedef __bf16 bf16x4 __attribute__((ext_vector_type(4)));
typedef __bf16 bf16x8 __attribute__((ext_vector_type(8)));
typedef float  f32x4  __attribute__((ext_vector_type(4)));

__device__ __forceinline__ f32x4 mfma16(bf16x8 a, bf16x8 b, f32x4 c) {
  // D[m][n] += sum_k A[m][k]*B[k][n]
  // A frag: lane holds row (lane&15), k = (lane>>4)*8 + e
  // B frag: lane holds col (lane&15), k = (lane>>4)*8 + e
  // D frag: col = lane&15, row = (lane>>4)*4 + reg
  return __builtin_amdgcn_mfma_f32_16x16x32_bf16(a, b, c, 0, 0, 0);
}

__device__ __forceinline__ bf16_t to_bf(float x) { return (bf16_t)x; }

// ---------------------------------------------------------------------------
// Kernel 1: QKV projection.  grid (128 Mtiles, 12 col-panels), 256 threads.
// panels 0-3 -> Q cols 0..511, 4-7 -> K, 8-11 -> V.
// Writes Qhi/Qlo/Khi/Klo [16384][512] bf16, Vt [8][512][2048] bf16.
// ---------------------------------------------------------------------------
__global__ __launch_bounds__(256, 2) void k_proj(
    const float* __restrict__ x,
    const float* __restrict__ Wq, const float* __restrict__ bq,
    const float* __restrict__ Wk, const float* __restrict__ bk,
    const float* __restrict__ Wv, const float* __restrict__ bv,
    bf16_t* __restrict__ Qhi, bf16_t* __restrict__ Qlo,
    bf16_t* __restrict__ Khi, bf16_t* __restrict__ Klo,
    bf16_t* __restrict__ Vt)
{
  __shared__ bf16_t xhi[128][40], xlo[128][40];   // [row][k], pad 40 (80 B rows)
  __shared__ bf16_t whi[128][40], wlo[128][40];   // [col][k] (transposed W)

  const int mt = blockIdx.x;      // 0..127
  const int jt = blockIdx.y;      // 0..11
  const int which = jt >> 2;      // 0=Q 1=K 2=V
  const float* __restrict__ W  = (which == 0) ? Wq : (which == 1) ? Wk : Wv;
  const float* __restrict__ bb = (which == 0) ? bq : (which == 1) ? bk : bv;
  const int jb = (jt & 3) * 128;  // col offset within this projection's 512

  const int tid  = threadIdx.x;
  const int lane = tid & 63;
  const int wave = tid >> 6;
  const int wr = wave >> 1, wc = wave & 1;   // 2x2 wave quadrants of 128x128
  const int l15 = lane & 15, lg = lane >> 4;

  f32x4 acc[4][4] = {};
  const int rowbase = mt * 128;

  for (int kb = 0; kb < 512; kb += 32) {
    __syncthreads();
    // ---- stage x tile (128 x 32 fp32 -> hi/lo bf16) ----
    {
      const int r0 = tid >> 3;          // 0..31
      const int c  = (tid & 7) * 4;     // 0,4,...,28
      #pragma unroll
      for (int p = 0; p < 4; ++p) {
        const int row = p * 32 + r0;
        const float4 v = *(const float4*)&x[(size_t)(rowbase + row) * 512 + kb + c];
        bf16x4 h, l;
        h[0] = to_bf(v.x); h[1] = to_bf(v.y); h[2] = to_bf(v.z); h[3] = to_bf(v.w);
        l[0] = to_bf(v.x - (float)h[0]); l[1] = to_bf(v.y - (float)h[1]);
        l[2] = to_bf(v.z - (float)h[2]); l[3] = to_bf(v.w - (float)h[3]);
        *(bf16x4*)&xhi[row][c] = h;
        *(bf16x4*)&xlo[row][c] = l;
      }
    }
    // ---- stage W tile transposed: whi[col][k] (each thread gathers a k-seg
    //      of one column; per-k the wave's loads are coalesced across cols) ----
    {
      const int col  = tid & 127;
      const int half = tid >> 7;  // 0..1
      #pragma unroll
      for (int s = 0; s < 2; ++s) {
        const int k0 = (half * 2 + s) * 8;  // 0,8 / 16,24
        bf16x8 h, l;
        #pragma unroll
        for (int j = 0; j < 8; ++j) {
          const float v = W[(size_t)(kb + k0 + j) * 512 + jb + col];
          h[j] = to_bf(v);
          l[j] = to_bf(v - (float)h[j]);
        }
        *(bf16x8*)&whi[col][k0] = h;
        *(bf16x8*)&wlo[col][k0] = l;
      }
    }
    __syncthreads();
    // ---- MFMA: 3-term split ----
    bf16x8 ah[4], al[4], bh[4], bl[4];
    #pragma unroll
    for (int g = 0; g < 4; ++g) {
      ah[g] = *(const bf16x8*)&xhi[wr * 64 + g * 16 + l15][lg * 8];
      al[g] = *(const bf16x8*)&xlo[wr * 64 + g * 16 + l15][lg * 8];
      bh[g] = *(const bf16x8*)&whi[wc * 64 + g * 16 + l15][lg * 8];
      bl[g] = *(const bf16x8*)&wlo[wc * 64 + g * 16 + l15][lg * 8];
    }
    #pragma unroll
    for (int i = 0; i < 4; ++i)
      #pragma unroll
      for (int j = 0; j < 4; ++j) {
        acc[i][j] = mfma16(ah[i], bh[j], acc[i][j]);
        acc[i][j] = mfma16(ah[i], bl[j], acc[i][j]);
        acc[i][j] = mfma16(al[i], bh[j], acc[i][j]);
      }
  }

  // ---- epilogue: add bias, split/convert, store ----
  #pragma unroll
  for (int j = 0; j < 4; ++j) {
    const int jl = jb + wc * 64 + j * 16 + l15;   // 0..511 within projection
    const float bias = bb[jl];
    #pragma unroll
    for (int i = 0; i < 4; ++i) {
      #pragma unroll
      for (int r = 0; r < 4; ++r) {
        const int row = rowbase + wr * 64 + i * 16 + lg * 4 + r;  // 0..16383
        const float y = acc[i][j][r] + bias;
        if (which == 2) {
          const int bat = row >> 11, n = row & 2047;
          Vt[((size_t)bat * 512 + jl) * 2048 + n] = to_bf(y);
        } else {
          const bf16_t h = to_bf(y);
          const bf16_t lo = to_bf(y - (float)h);
          bf16_t* hp = (which == 0) ? Qhi : Khi;
          bf16_t* lp = (which == 0) ? Qlo : Klo;
          hp[(size_t)row * 512 + jl] = h;
          lp[(size_t)row * 512 + jl] = lo;
        }
      }
    }
  }
}

// ---------------------------------------------------------------------------
// Kernel 2: S = Q K^T (per batch), hi/lo split.  grid (16,16,8), 256 threads.
// ---------------------------------------------------------------------------
__global__ __launch_bounds__(256, 2) void k_qk(
    const bf16_t* __restrict__ Qhi, const bf16_t* __restrict__ Qlo,
    const bf16_t* __restrict__ Khi, const bf16_t* __restrict__ Klo,
    float* __restrict__ S)
{
  __shared__ bf16_t ahi[128][40], alo[128][40];  // Q rows
  __shared__ bf16_t bhi[128][40], blo[128][40];  // K rows (j-dim)

  const int mt = blockIdx.x, nt = blockIdx.y, bat = blockIdx.z;
  const int tid = threadIdx.x, lane = tid & 63, wave = tid >> 6;
  const int wr = wave >> 1, wc = wave & 1, l15 = lane & 15, lg = lane >> 4;

  f32x4 acc[4][4] = {};
  const size_t arow0 = (size_t)bat * 2048 + mt * 128;
  const size_t brow0 = (size_t)bat * 2048 + nt * 128;

  for (int kb = 0; kb < 512; kb += 32) {
    __syncthreads();
    const int r  = tid >> 1;          // 0..127
    const int s0 = (tid & 1) * 2;     // 2 16B-slots each
    #pragma unroll
    for (int s = 0; s < 2; ++s) {
      const int c = (s0 + s) * 8;     // 0,8 / 16,24
      *(bf16x8*)&ahi[r][c] = *(const bf16x8*)&Qhi[(arow0 + r) * 512 + kb + c];
      *(bf16x8*)&alo[r][c] = *(const bf16x8*)&Qlo[(arow0 + r) * 512 + kb + c];
      *(bf16x8*)&bhi[r][c] = *(const bf16x8*)&Khi[(brow0 + r) * 512 + kb + c];
      *(bf16x8*)&blo[r][c] = *(const bf16x8*)&Klo[(brow0 + r) * 512 + kb + c];
    }
    __syncthreads();
    bf16x8 ah[4], al[4], bh[4], bl[4];
    #pragma unroll
    for (int g = 0; g < 4; ++g) {
      ah[g] = *(const bf16x8*)&ahi[wr * 64 + g * 16 + l15][lg * 8];
      al[g] = *(const bf16x8*)&alo[wr * 64 + g * 16 + l15][lg * 8];
      bh[g] = *(const bf16x8*)&bhi[wc * 64 + g * 16 + l15][lg * 8];
      bl[g] = *(const bf16x8*)&blo[wc * 64 + g * 16 + l15][lg * 8];
    }
    #pragma unroll
    for (int i = 0; i < 4; ++i)
      #pragma unroll
      for (int j = 0; j < 4; ++j) {
        acc[i][j] = mfma16(ah[i], bh[j], acc[i][j]);
        acc[i][j] = mfma16(ah[i], bl[j], acc[i][j]);
        acc[i][j] = mfma16(al[i], bh[j], acc[i][j]);
      }
  }

  #pragma unroll
  for (int i = 0; i < 4; ++i)
    #pragma unroll
    for (int j = 0; j < 4; ++j)
      #pragma unroll
      for (int r = 0; r < 4; ++r) {
        const int ii = mt * 128 + wr * 64 + i * 16 + lg * 4 + r;
        const int jj = nt * 128 + wc * 64 + j * 16 + l15;
        S[((size_t)bat * 2048 + ii) * 2048 + jj] = acc[i][j][r];
      }
}

// ---------------------------------------------------------------------------
// Kernel 3: row softmax.  grid 16384 blocks (one per row), 256 threads.
// Reads S row (fp32), writes unnormalized P=exp(s-m) as bf16 overlaid into
// the first 4 KB of the same row, and linv[row] = sqrt(512)/sum.
// ---------------------------------------------------------------------------
__global__ __launch_bounds__(256) void k_softmax(float* __restrict__ S,
                                                 float* __restrict__ linv)
{
  __shared__ float red[4];
  const int row = blockIdx.x;
  const int tid = threadIdx.x, lane = tid & 63, wave = tid >> 6;
  float* srow = S + (size_t)row * 2048;

  float v[8];
  {
    const float4 a = *(const float4*)&srow[tid * 8];
    const float4 b = *(const float4*)&srow[tid * 8 + 4];
    v[0] = a.x; v[1] = a.y; v[2] = a.z; v[3] = a.w;
    v[4] = b.x; v[5] = b.y; v[6] = b.z; v[7] = b.w;
  }
  float m = v[0];
  #pragma unroll
  for (int i = 1; i < 8; ++i) m = fmaxf(m, v[i]);
  #pragma unroll
  for (int off = 1; off < 64; off <<= 1) m = fmaxf(m, __shfl_xor(m, off));
  if (lane == 0) red[wave] = m;
  __syncthreads();
  m = fmaxf(fmaxf(red[0], red[1]), fmaxf(red[2], red[3]));
  __syncthreads();  // before red[] reuse

  bf16x8 pb;
  float sum = 0.f;
  #pragma unroll
  for (int i = 0; i < 8; ++i) {
    const float e = __expf(v[i] - m);
    const bf16_t eb = to_bf(e);    // round first so numerator/denominator match
    pb[i] = eb;
    sum += (float)eb;
  }
  #pragma unroll
  for (int off = 1; off < 64; off <<= 1) sum += __shfl_xor(sum, off);
  if (lane == 0) red[wave] = sum;
  __syncthreads();
  const float L = red[0] + red[1] + red[2] + red[3];

  // overlay write: bytes [16*tid, 16*tid+16) of this row; all reads of the
  // row happened before the barriers above.
  *(bf16x8*)((bf16_t*)srow + tid * 8) = pb;
  if (tid == 0) linv[row] = 22.62741699796952f / L;  // sqrt(512)/sum
}

// ---------------------------------------------------------------------------
// Kernel 4: out = (P @ V) * linv.  grid (16,4,8), 256 threads.  BK=64.
// P rows are bf16 at byte stride 8192 inside the S buffer; Vt is [b][dv][n].
// ---------------------------------------------------------------------------
__global__ __launch_bounds__(256, 2) void k_pv(
    const float* __restrict__ Sbuf, const bf16_t* __restrict__ Vt,
    const float* __restrict__ linv, float* __restrict__ out)
{
  __shared__ bf16_t pa[128][72];   // [q-row][kv], 144 B rows
  __shared__ bf16_t vb[128][72];   // [dv][kv]

  const int mt = blockIdx.x, nt = blockIdx.y, bat = blockIdx.z;
  const int tid = threadIdx.x, lane = tid & 63, wave = tid >> 6;
  const int wr = wave >> 1, wc = wave & 1, l15 = lane & 15, lg = lane >> 4;

  f32x4 acc[4][4] = {};

  for (int kb = 0; kb < 2048; kb += 64) {
    __syncthreads();
    const int r  = tid >> 1;          // 0..127
    const int s0 = (tid & 1) * 4;     // 4 16B-slots each
    const bf16_t* prow =
        (const bf16_t*)(Sbuf + ((size_t)bat * 2048 + mt * 128 + r) * 2048) + kb;
    const bf16_t* vrow = &Vt[((size_t)bat * 512 + nt * 128 + r) * 2048 + kb];
    #pragma unroll
    for (int s = 0; s < 4; ++s) {
      const int c = (s0 + s) * 8;     // 0..56 step 8
      *(bf16x8*)&pa[r][c] = *(const bf16x8*)&prow[c];
      *(bf16x8*)&vb[r][c] = *(const bf16x8*)&vrow[c];
    }
    __syncthreads();
    #pragma unroll
    for (int kk = 0; kk < 64; kk += 32) {
      bf16x8 af[4], bfr[4];
      #pragma unroll
      for (int g = 0; g < 4; ++g) {
        af[g]  = *(const bf16x8*)&pa[wr * 64 + g * 16 + l15][kk + lg * 8];
        bfr[g] = *(const bf16x8*)&vb[wc * 64 + g * 16 + l15][kk + lg * 8];
      }
      #pragma unroll
      for (int i = 0; i < 4; ++i)
        #pragma unroll
        for (int j = 0; j < 4; ++j)
          acc[i][j] = mfma16(af[i], bfr[j], acc[i][j]);
    }
  }

  #pragma unroll
  for (int i = 0; i < 4; ++i)
    #pragma unroll
    for (int r = 0; r < 4; ++r) {
      const int ii = mt * 128 + wr * 64 + i * 16 + lg * 4 + r;   // row in batch
      const float li = linv[(size_t)bat * 2048 + ii];
      #pragma unroll
      for (int j = 0; j < 4; ++j) {
        const int dv = nt * 128 + wc * 64 + j * 16 + l15;
        out[((size_t)bat * 2048 + ii) * 512 + dv] = acc[i][j][r] * li;
      }
    }
}

// ---------------------------------------------------------------------------
extern "C" void kernel_launch(void* const* d_in, const int* in_sizes, int n_in,
                              void* d_out, int out_size, void* d_ws, size_t ws_size,
                              hipStream_t stream) {
  const float* x  = (const float*)d_in[0];
  const float* Wq = (const float*)d_in[1];
  const float* bq = (const float*)d_in[2];
  const float* Wk = (const float*)d_in[3];
  const float* bk = (const float*)d_in[4];
  const float* Wv = (const float*)d_in[5];
  const float* bv = (const float*)d_in[6];
  float* out = (float*)d_out;

  char* ws = (char*)d_ws;
  const size_t SZ = (size_t)16384 * 512 * 2;       // 16,777,216 B per bf16 buf
  bf16_t* Qhi = (bf16_t*)(ws + 0 * SZ);
  bf16_t* Qlo = (bf16_t*)(ws + 1 * SZ);
  bf16_t* Khi = (bf16_t*)(ws + 2 * SZ);
  bf16_t* Klo = (bf16_t*)(ws + 3 * SZ);
  bf16_t* Vt  = (bf16_t*)(ws + 4 * SZ);
  float*  S   = (float*)(ws + 5 * SZ);             // 134,217,728 B
  float*  linv = (float*)(ws + 5 * SZ + (size_t)134217728);

  k_proj<<<dim3(128, 12), 256, 0, stream>>>(x, Wq, bq, Wk, bk, Wv, bv,
                                            Qhi, Qlo, Khi, Klo, Vt);
  k_qk<<<dim3(16, 16, 8), 256, 0, stream>>>(Qhi, Qlo, Khi, Klo, S);
  k_softmax<<<16384, 256, 0, stream>>>(S, linv);
  k_pv<<<dim3(16, 4, 8), 256, 0, stream>>>(S, Vt, linv, out);
}

// Round 2
// 196.445 us; speedup vs baseline: 1.9205x; 1.9205x over previous
//
#include <hip/hip_runtime.h>
#include <stdint.h>
#include <stddef.h>

// ---------------------------------------------------------------------------
// out = softmax(Q K^T) * sqrt(512) @ V,  Q=x Wq+bq etc.  B=8,N=2048,D=512.
// Round 2: pre-converted bf16 hi/lo inputs; proj = 3-term bf16 split MFMA;
// Q,K,P,V stored fp16; qk/pv single-term fp16 MFMA; global_load_lds staging
// with XOR-swizzled source + swizzled ds_read (conflict-free b128).
// ws layout (B):
//   xh 0, xl 16777216 (linv aliases xl after proj), Q 33554432, K 50331648,
//   Vt 67108864, S 83886080 (134217728; Wth/Wtl alias its head pre-qk;
//   P fp16 overlays S rows after softmax).  total 218103808.
// ---------------------------------------------------------------------------

typedef __bf16 bf16_t;
typedef _Float16 f16_t;
typedef __bf16 bf16x8 __attribute__((ext_vector_type(8)));
typedef _Float16 f16x8 __attribute__((ext_vector_type(8)));
typedef float  f32x4  __attribute__((ext_vector_type(4)));

__device__ __forceinline__ f32x4 mfma_bf(bf16x8 a, bf16x8 b, f32x4 c) {
  return __builtin_amdgcn_mfma_f32_16x16x32_bf16(a, b, c, 0, 0, 0);
}
__device__ __forceinline__ f32x4 mfma_h(f16x8 a, f16x8 b, f32x4 c) {
  return __builtin_amdgcn_mfma_f32_16x16x32_f16(a, b, c, 0, 0, 0);
}

// async global->LDS, 16 B per lane; LDS dest = wave-uniform base + lane*16
__device__ __forceinline__ void gl_lds16(const void* g, void* lds) {
  __builtin_amdgcn_global_load_lds(
      (const __attribute__((address_space(1))) unsigned int*)g,
      (__attribute__((address_space(3))) unsigned int*)lds, 16, 0, 0);
}

// Stage a [128][64] 2-byte-elem tile (16 KB) from row-major global.
// Linear LDS dest; source pre-swizzled so that phys slot s of row r holds
// logical slot s^(r&7)  (16B slots, 8 per 128B row).
template <typename T>
__device__ __forceinline__ void stage_tile(T* lds, const T* g, size_t gstride,
                                           int wave, int lane) {
  const int l8 = lane >> 3;            // row-within-chunk == row&7
  const int lslot = (lane & 7) ^ l8;   // logical slot to fetch
  #pragma unroll
  for (int c = 0; c < 4; ++c) {
    const int chunk = wave * 4 + c;    // 16 x 1KB chunks
    const int row = chunk * 8 + l8;
    gl_lds16(g + (size_t)row * gstride + lslot * 8, lds + chunk * 512);
  }
}

// Swizzled fragment read: logical (row R, 8 elems at col slot*8)
template <typename V, typename T>
__device__ __forceinline__ V lds_frag(const T* buf, int R, int slot) {
  return *(const V*)&buf[R * 64 + (((slot ^ (R & 7)) & 7) << 3)];
}

// ---------------------------------------------------------------------------
// convert x -> bf16 hi/lo
__global__ __launch_bounds__(256) void k_conv_x(const float* __restrict__ x,
                                                bf16_t* __restrict__ xh,
                                                bf16_t* __restrict__ xl) {
  const int i = (blockIdx.x * 256 + threadIdx.x) * 8;
  const float4 a = *(const float4*)&x[i];
  const float4 b = *(const float4*)&x[i + 4];
  float v[8] = {a.x, a.y, a.z, a.w, b.x, b.y, b.z, b.w};
  bf16x8 h, l;
  #pragma unroll
  for (int j = 0; j < 8; ++j) {
    h[j] = (bf16_t)v[j];
    l[j] = (bf16_t)(v[j] - (float)h[j]);
  }
  *(bf16x8*)&xh[i] = h;
  *(bf16x8*)&xl[i] = l;
}

// convert+transpose W -> Wt[p][n][k] bf16 hi/lo
__global__ __launch_bounds__(256) void k_conv_w(const float* __restrict__ Wq,
                                                const float* __restrict__ Wk,
                                                const float* __restrict__ Wv,
                                                bf16_t* __restrict__ Wth,
                                                bf16_t* __restrict__ Wtl) {
  __shared__ float t[64][65];
  const int p = blockIdx.z;
  const float* __restrict__ W = (p == 0) ? Wq : (p == 1) ? Wk : Wv;
  const int n0 = blockIdx.x * 64, k0 = blockIdx.y * 64;
  const int tx = threadIdx.x & 63, ty = threadIdx.x >> 6;
  #pragma unroll
  for (int j = 0; j < 16; ++j)
    t[ty * 16 + j][tx] = W[(size_t)(k0 + ty * 16 + j) * 512 + n0 + tx];
  __syncthreads();
  #pragma unroll
  for (int j = 0; j < 16; ++j) {
    const int nl = ty * 16 + j;
    const float v = t[tx][nl];
    const bf16_t h = (bf16_t)v;
    const size_t idx = (size_t)p * 262144 + (size_t)(n0 + nl) * 512 + k0 + tx;
    Wth[idx] = h;
    Wtl[idx] = (bf16_t)(v - (float)h);
  }
}

// ---------------------------------------------------------------------------
// Projection: grid (128 mt, 12 panels).  panels 0-3 Q, 4-7 K, 8-11 V.
// Q,K: 3-term bf16 split -> fp16 out.  V: 1-term -> transposed fp16 Vt.
// ---------------------------------------------------------------------------
__global__ __launch_bounds__(256, 2) void k_proj(
    const bf16_t* __restrict__ xh, const bf16_t* __restrict__ xl,
    const bf16_t* __restrict__ Wth, const bf16_t* __restrict__ Wtl,
    const float* __restrict__ bq, const float* __restrict__ bk,
    const float* __restrict__ bv,
    f16_t* __restrict__ Q, f16_t* __restrict__ K, f16_t* __restrict__ Vt)
{
  __shared__ __align__(16) bf16_t smem[4][128 * 64];  // Ah, Al, Bh, Bl
  bf16_t* Ah = smem[0];
  bf16_t* Al = smem[1];
  bf16_t* Bh = smem[2];
  bf16_t* Bl = smem[3];

  const int mt = blockIdx.x, jt = blockIdx.y;
  const int which = jt >> 2;            // 0=Q 1=K 2=V
  const int jb = (jt & 3) * 128;
  const bool isV = (which == 2);

  const int tid = threadIdx.x, lane = tid & 63, wave = tid >> 6;
  const int wr = wave >> 1, wc = wave & 1, l15 = lane & 15, lg = lane >> 4;
  const int rowbase = mt * 128;

  const bf16_t* Wh = Wth + (size_t)which * 262144 + (size_t)jb * 512;
  const bf16_t* Wl = Wtl + (size_t)which * 262144 + (size_t)jb * 512;

  f32x4 acc[4][4] = {};

  for (int kb = 0; kb < 512; kb += 64) {
    __syncthreads();
    stage_tile(Ah, xh + (size_t)rowbase * 512 + kb, 512, wave, lane);
    stage_tile(Bh, Wh + kb, 512, wave, lane);
    if (!isV) {
      stage_tile(Al, xl + (size_t)rowbase * 512 + kb, 512, wave, lane);
      stage_tile(Bl, Wl + kb, 512, wave, lane);
    }
    __syncthreads();
    #pragma unroll
    for (int h = 0; h < 2; ++h) {
      const int slot0 = h * 4 + lg;
      bf16x8 ah[4], bh[4];
      #pragma unroll
      for (int g = 0; g < 4; ++g) {
        ah[g] = lds_frag<bf16x8>(Ah, wr * 64 + g * 16 + l15, slot0);
        bh[g] = lds_frag<bf16x8>(Bh, wc * 64 + g * 16 + l15, slot0);
      }
      #pragma unroll
      for (int i = 0; i < 4; ++i)
        #pragma unroll
        for (int j = 0; j < 4; ++j)
          acc[i][j] = mfma_bf(ah[i], bh[j], acc[i][j]);
      if (!isV) {
        bf16x8 al[4], bl[4];
        #pragma unroll
        for (int g = 0; g < 4; ++g) {
          al[g] = lds_frag<bf16x8>(Al, wr * 64 + g * 16 + l15, slot0);
          bl[g] = lds_frag<bf16x8>(Bl, wc * 64 + g * 16 + l15, slot0);
        }
        #pragma unroll
        for (int i = 0; i < 4; ++i)
          #pragma unroll
          for (int j = 0; j < 4; ++j) {
            acc[i][j] = mfma_bf(al[i], bh[j], acc[i][j]);
            acc[i][j] = mfma_bf(ah[i], bl[j], acc[i][j]);
          }
      }
    }
  }

  if (!isV) {
    f16_t* __restrict__ O = (which == 0) ? Q : K;
    const float* __restrict__ bb = (which == 0) ? bq : bk;
    #pragma unroll
    for (int j = 0; j < 4; ++j) {
      const int jl = jb + wc * 64 + j * 16 + l15;
      const float bias = bb[jl];
      #pragma unroll
      for (int i = 0; i < 4; ++i)
        #pragma unroll
        for (int r = 0; r < 4; ++r) {
          const int row = rowbase + wr * 64 + i * 16 + lg * 4 + r;
          O[(size_t)row * 512 + jl] = (f16_t)(acc[i][j][r] + bias);
        }
    }
  } else {
    // transpose 128x128 tile through LDS, then coalesced Vt stores
    __syncthreads();
    f16_t* vtl = (f16_t*)smem;          // [128][136] f16 = 34816 B
    #pragma unroll
    for (int j = 0; j < 4; ++j) {
      const int jj = wc * 64 + j * 16 + l15;
      const float bias = bv[jb + jj];
      #pragma unroll
      for (int i = 0; i < 4; ++i)
        #pragma unroll
        for (int r = 0; r < 4; ++r) {
          const int ii = wr * 64 + i * 16 + lg * 4 + r;
          vtl[jj * 136 + ii] = (f16_t)(acc[i][j][r] + bias);
        }
    }
    __syncthreads();
    const int dv = tid >> 1, hf = tid & 1;
    const int bat = rowbase >> 11, n0 = rowbase & 2047;
    f16_t* __restrict__ dst =
        &Vt[((size_t)bat * 512 + jb + dv) * 2048 + n0 + hf * 64];
    const f16_t* src = &vtl[dv * 136 + hf * 64];
    #pragma unroll
    for (int s = 0; s < 8; ++s)
      *(f16x8*)&dst[s * 8] = *(const f16x8*)&src[s * 8];
  }
}

// ---------------------------------------------------------------------------
// S = Q K^T, single-term fp16.  grid (16,16,8).
// ---------------------------------------------------------------------------
__global__ __launch_bounds__(256, 2) void k_qk(const f16_t* __restrict__ Q,
                                               const f16_t* __restrict__ K,
                                               float* __restrict__ S)
{
  __shared__ __align__(16) f16_t A[128 * 64];
  __shared__ __align__(16) f16_t Bt[128 * 64];

  const int mt = blockIdx.x, nt = blockIdx.y, bat = blockIdx.z;
  const int tid = threadIdx.x, lane = tid & 63, wave = tid >> 6;
  const int wr = wave >> 1, wc = wave & 1, l15 = lane & 15, lg = lane >> 4;

  f32x4 acc[4][4] = {};
  const f16_t* Abase = Q + ((size_t)bat * 2048 + mt * 128) * 512;
  const f16_t* Bbase = K + ((size_t)bat * 2048 + nt * 128) * 512;

  for (int kb = 0; kb < 512; kb += 64) {
    __syncthreads();
    stage_tile(A, Abase + kb, 512, wave, lane);
    stage_tile(Bt, Bbase + kb, 512, wave, lane);
    __syncthreads();
    #pragma unroll
    for (int h = 0; h < 2; ++h) {
      const int slot0 = h * 4 + lg;
      f16x8 af[4], bf[4];
      #pragma unroll
      for (int g = 0; g < 4; ++g) {
        af[g] = lds_frag<f16x8>(A, wr * 64 + g * 16 + l15, slot0);
        bf[g] = lds_frag<f16x8>(Bt, wc * 64 + g * 16 + l15, slot0);
      }
      #pragma unroll
      for (int i = 0; i < 4; ++i)
        #pragma unroll
        for (int j = 0; j < 4; ++j)
          acc[i][j] = mfma_h(af[i], bf[j], acc[i][j]);
    }
  }

  #pragma unroll
  for (int i = 0; i < 4; ++i)
    #pragma unroll
    for (int j = 0; j < 4; ++j)
      #pragma unroll
      for (int r = 0; r < 4; ++r) {
        const int ii = mt * 128 + wr * 64 + i * 16 + lg * 4 + r;
        const int jj = nt * 128 + wc * 64 + j * 16 + l15;
        S[((size_t)bat * 2048 + ii) * 2048 + jj] = acc[i][j][r];
      }
}

// ---------------------------------------------------------------------------
// Row softmax: fp32 S row -> unnormalized fp16 P overlaid; linv = sqrt(512)/L
// ---------------------------------------------------------------------------
__global__ __launch_bounds__(256) void k_softmax(float* __restrict__ S,
                                                 float* __restrict__ linv)
{
  __shared__ float red[4];
  const int row = blockIdx.x;
  const int tid = threadIdx.x, lane = tid & 63, wave = tid >> 6;
  float* srow = S + (size_t)row * 2048;

  float v[8];
  {
    const float4 a = *(const float4*)&srow[tid * 8];
    const float4 b = *(const float4*)&srow[tid * 8 + 4];
    v[0] = a.x; v[1] = a.y; v[2] = a.z; v[3] = a.w;
    v[4] = b.x; v[5] = b.y; v[6] = b.z; v[7] = b.w;
  }
  float m = v[0];
  #pragma unroll
  for (int i = 1; i < 8; ++i) m = fmaxf(m, v[i]);
  #pragma unroll
  for (int off = 1; off < 64; off <<= 1) m = fmaxf(m, __shfl_xor(m, off));
  if (lane == 0) red[wave] = m;
  __syncthreads();
  m = fmaxf(fmaxf(red[0], red[1]), fmaxf(red[2], red[3]));
  __syncthreads();

  f16x8 pb;
  float sum = 0.f;
  #pragma unroll
  for (int i = 0; i < 8; ++i) {
    const float e = __expf(v[i] - m);
    const f16_t eh = (f16_t)e;
    pb[i] = eh;
    sum += (float)eh;
  }
  #pragma unroll
  for (int off = 1; off < 64; off <<= 1) sum += __shfl_xor(sum, off);
  if (lane == 0) red[wave] = sum;
  __syncthreads();
  const float L = red[0] + red[1] + red[2] + red[3];

  *(f16x8*)((f16_t*)srow + tid * 8) = pb;
  if (tid == 0) linv[row] = 22.62741699796952f / L;
}

// ---------------------------------------------------------------------------
// out = (P @ V) * linv.  grid (16,4,8).  P fp16 rows at 8192 B pitch in S.
// ---------------------------------------------------------------------------
__global__ __launch_bounds__(256, 2) void k_pv(const float* __restrict__ Sbuf,
                                               const f16_t* __restrict__ Vt,
                                               const float* __restrict__ linv,
                                               float* __restrict__ out)
{
  __shared__ __align__(16) f16_t A[128 * 64];
  __shared__ __align__(16) f16_t Bv[128 * 64];

  const int mt = blockIdx.x, nt = blockIdx.y, bat = blockIdx.z;
  const int tid = threadIdx.x, lane = tid & 63, wave = tid >> 6;
  const int wr = wave >> 1, wc = wave & 1, l15 = lane & 15, lg = lane >> 4;

  f32x4 acc[4][4] = {};
  const f16_t* Abase = (const f16_t*)(Sbuf + ((size_t)bat * 2048 + mt * 128) * 2048);
  const f16_t* Bbase = Vt + ((size_t)bat * 512 + nt * 128) * 2048;

  for (int kb = 0; kb < 2048; kb += 64) {
    __syncthreads();
    stage_tile(A, Abase + kb, 4096, wave, lane);   // P row pitch 4096 f16
    stage_tile(Bv, Bbase + kb, 2048, wave, lane);
    __syncthreads();
    #pragma unroll
    for (int h = 0; h < 2; ++h) {
      const int slot0 = h * 4 + lg;
      f16x8 af[4], bf[4];
      #pragma unroll
      for (int g = 0; g < 4; ++g) {
        af[g] = lds_frag<f16x8>(A, wr * 64 + g * 16 + l15, slot0);
        bf[g] = lds_frag<f16x8>(Bv, wc * 64 + g * 16 + l15, slot0);
      }
      #pragma unroll
      for (int i = 0; i < 4; ++i)
        #pragma unroll
        for (int j = 0; j < 4; ++j)
          acc[i][j] = mfma_h(af[i], bf[j], acc[i][j]);
    }
  }

  #pragma unroll
  for (int i = 0; i < 4; ++i)
    #pragma unroll
    for (int r = 0; r < 4; ++r) {
      const int ii = mt * 128 + wr * 64 + i * 16 + lg * 4 + r;
      const float li = linv[(size_t)bat * 2048 + ii];
      #pragma unroll
      for (int j = 0; j < 4; ++j) {
        const int dv = nt * 128 + wc * 64 + j * 16 + l15;
        out[((size_t)bat * 2048 + ii) * 512 + dv] = acc[i][j][r] * li;
      }
    }
}

// ---------------------------------------------------------------------------
extern "C" void kernel_launch(void* const* d_in, const int* in_sizes, int n_in,
                              void* d_out, int out_size, void* d_ws, size_t ws_size,
                              hipStream_t stream) {
  const float* x  = (const float*)d_in[0];
  const float* Wq = (const float*)d_in[1];
  const float* bq = (const float*)d_in[2];
  const float* Wk = (const float*)d_in[3];
  const float* bk = (const float*)d_in[4];
  const float* Wv = (const float*)d_in[5];
  const float* bv = (const float*)d_in[6];
  float* out = (float*)d_out;

  char* ws = (char*)d_ws;
  bf16_t* xh  = (bf16_t*)(ws + 0);
  bf16_t* xl  = (bf16_t*)(ws + 16777216);
  float*  linv = (float*)(ws + 16777216);          // aliases xl (dead after proj)
  f16_t*  Q   = (f16_t*)(ws + 33554432);
  f16_t*  K   = (f16_t*)(ws + 50331648);
  f16_t*  Vt  = (f16_t*)(ws + 67108864);
  float*  S   = (float*)(ws + 83886080);
  bf16_t* Wth = (bf16_t*)(ws + 83886080);          // aliases S head (dead pre-qk)
  bf16_t* Wtl = (bf16_t*)(ws + 83886080 + 1572864);

  k_conv_x<<<4096, 256, 0, stream>>>(x, xh, xl);
  k_conv_w<<<dim3(8, 8, 3), 256, 0, stream>>>(Wq, Wk, Wv, Wth, Wtl);
  k_proj<<<dim3(128, 12), 256, 0, stream>>>(xh, xl, Wth, Wtl, bq, bk, bv, Q, K, Vt);
  k_qk<<<dim3(16, 16, 8), 256, 0, stream>>>(Q, K, S);
  k_softmax<<<16384, 256, 0, stream>>>(S, linv);
  k_pv<<<dim3(16, 4, 8), 256, 0, stream>>>(S, Vt, linv, out);
}

// Round 3
// 184.998 us; speedup vs baseline: 2.0394x; 1.0619x over previous
//
#include <hip/hip_runtime.h>
#include <stdint.h>
#include <stddef.h>

// ---------------------------------------------------------------------------
// out = softmax(x Wq+bq @ (x Wk+bk)^T) * sqrt(512) @ (x Wv+bv)
// B=8, N=2048, D=DK=DV=512, fp32 I/O.
// Round 3: single-term fp16 MFMA everywhere (score error ~0.016 sigma, under
// the fp16-storage floor x1.75). No softmax kernel: k_qk atomicMax's an
// encoded row-max; k_pv does exp-on-stage and accumulates the row sum l
// inside its kv loop. XCD-chunked block swizzle on all GEMMs.
// ws layout (B): x16 0, Q 16777216, K 33554432, Vt 50331648,
//   S 67108864 (134217728), Wt 201326592 (1572864), mEnc 202899456 (65536).
//   total 202964992.
// ---------------------------------------------------------------------------

typedef _Float16 f16_t;
typedef _Float16 f16x8 __attribute__((ext_vector_type(8)));
typedef float    f32x4 __attribute__((ext_vector_type(4)));

__device__ __forceinline__ f32x4 mfma_h(f16x8 a, f16x8 b, f32x4 c) {
  // D frag: col = lane&15, row = (lane>>4)*4 + reg
  return __builtin_amdgcn_mfma_f32_16x16x32_f16(a, b, c, 0, 0, 0);
}

__device__ __forceinline__ void gl_lds16(const void* g, void* lds) {
  __builtin_amdgcn_global_load_lds(
      (const __attribute__((address_space(1))) unsigned int*)g,
      (__attribute__((address_space(3))) unsigned int*)lds, 16, 0, 0);
}

// Stage a [128][64] f16 tile (16 KB) from row-major global via global_load_lds.
// Linear LDS dest; source pre-swizzled: phys slot s of row r holds logical
// slot s^(r&7) (16B slots, 8 per 128B row).
__device__ __forceinline__ void stage_tile(f16_t* lds, const f16_t* g,
                                           size_t gstride, int wave, int lane) {
  const int l8 = lane >> 3;
  const int lslot = (lane & 7) ^ l8;
  #pragma unroll
  for (int c = 0; c < 4; ++c) {
    const int chunk = wave * 4 + c;
    const int row = chunk * 8 + l8;
    gl_lds16(g + (size_t)row * gstride + lslot * 8, lds + chunk * 512);
  }
}

// Swizzled fragment read: logical (row R, 8 elems at col slot*8)
__device__ __forceinline__ f16x8 lds_frag(const f16_t* buf, int R, int slot) {
  return *(const f16x8*)&buf[R * 64 + (((slot ^ (R & 7)) & 7) << 3)];
}

// monotonic float<->uint encoding for atomicMax (memset-0 == -huge sentinel)
__device__ __forceinline__ unsigned int fenc(float f) {
  unsigned int u = __float_as_uint(f);
  return (u & 0x80000000u) ? ~u : (u | 0x80000000u);
}
__device__ __forceinline__ float fdec(unsigned int e) {
  unsigned int u = (e & 0x80000000u) ? (e & 0x7fffffffu) : ~e;
  return __uint_as_float(u);
}

// XCD-chunked work remap (requires nwg % 8 == 0)
__device__ __forceinline__ int xcd_swz(int id, int nwg) {
  return (id & 7) * (nwg >> 3) + (id >> 3);
}

// ---------------------------------------------------------------------------
__global__ __launch_bounds__(256) void k_conv_x(const float* __restrict__ x,
                                                f16_t* __restrict__ x16) {
  const int i = (blockIdx.x * 256 + threadIdx.x) * 8;
  const float4 a = *(const float4*)&x[i];
  const float4 b = *(const float4*)&x[i + 4];
  float v[8] = {a.x, a.y, a.z, a.w, b.x, b.y, b.z, b.w};
  f16x8 h;
  #pragma unroll
  for (int j = 0; j < 8; ++j) h[j] = (f16_t)v[j];
  *(f16x8*)&x16[i] = h;
}

// transpose+convert W -> Wt[p][n][k] f16
__global__ __launch_bounds__(256) void k_conv_w(const float* __restrict__ Wq,
                                                const float* __restrict__ Wk,
                                                const float* __restrict__ Wv,
                                                f16_t* __restrict__ Wt) {
  __shared__ float t[64][65];
  const int p = blockIdx.z;
  const float* __restrict__ W = (p == 0) ? Wq : (p == 1) ? Wk : Wv;
  const int n0 = blockIdx.x * 64, k0 = blockIdx.y * 64;
  const int tx = threadIdx.x & 63, ty = threadIdx.x >> 6;
  #pragma unroll
  for (int j = 0; j < 16; ++j)
    t[ty * 16 + j][tx] = W[(size_t)(k0 + ty * 16 + j) * 512 + n0 + tx];
  __syncthreads();
  #pragma unroll
  for (int j = 0; j < 16; ++j) {
    const int nl = ty * 16 + j;
    Wt[(size_t)p * 262144 + (size_t)(n0 + nl) * 512 + k0 + tx] =
        (f16_t)t[tx][nl];
  }
}

// ---------------------------------------------------------------------------
// Projection: flat grid 1536 (xcd-swizzled -> mt*12+jt).  Single fp16 MFMA.
// panels 0-3 Q, 4-7 K, 8-11 V (V transposed to Vt[b][dv][n]).
// ---------------------------------------------------------------------------
__global__ __launch_bounds__(256, 2) void k_proj(
    const f16_t* __restrict__ x16, const f16_t* __restrict__ Wt,
    const float* __restrict__ bq, const float* __restrict__ bk,
    const float* __restrict__ bv,
    f16_t* __restrict__ Q, f16_t* __restrict__ K, f16_t* __restrict__ Vt)
{
  __shared__ __align__(16) unsigned char smem[34816];  // A,B tiles / vtl
  f16_t* A = (f16_t*)smem;
  f16_t* B = (f16_t*)(smem + 16384);

  const int wg = xcd_swz(blockIdx.x, 1536);
  const int mt = wg / 12, jt = wg % 12;
  const int which = jt >> 2;            // 0=Q 1=K 2=V
  const int jb = (jt & 3) * 128;

  const int tid = threadIdx.x, lane = tid & 63, wave = tid >> 6;
  const int wr = wave >> 1, wc = wave & 1, l15 = lane & 15, lg = lane >> 4;
  const int rowbase = mt * 128;

  const f16_t* Wbase = Wt + (size_t)which * 262144 + (size_t)jb * 512;

  f32x4 acc[4][4] = {};

  for (int kb = 0; kb < 512; kb += 64) {
    __syncthreads();
    stage_tile(A, x16 + (size_t)rowbase * 512 + kb, 512, wave, lane);
    stage_tile(B, Wbase + kb, 512, wave, lane);
    __syncthreads();
    #pragma unroll
    for (int h = 0; h < 2; ++h) {
      const int slot0 = h * 4 + lg;
      f16x8 af[4], bf[4];
      #pragma unroll
      for (int g = 0; g < 4; ++g) {
        af[g] = lds_frag(A, wr * 64 + g * 16 + l15, slot0);
        bf[g] = lds_frag(B, wc * 64 + g * 16 + l15, slot0);
      }
      #pragma unroll
      for (int i = 0; i < 4; ++i)
        #pragma unroll
        for (int j = 0; j < 4; ++j)
          acc[i][j] = mfma_h(af[i], bf[j], acc[i][j]);
    }
  }

  if (which != 2) {
    f16_t* __restrict__ O = (which == 0) ? Q : K;
    const float* __restrict__ bb = (which == 0) ? bq : bk;
    #pragma unroll
    for (int j = 0; j < 4; ++j) {
      const int jl = jb + wc * 64 + j * 16 + l15;
      const float bias = bb[jl];
      #pragma unroll
      for (int i = 0; i < 4; ++i)
        #pragma unroll
        for (int r = 0; r < 4; ++r) {
          const int row = rowbase + wr * 64 + i * 16 + lg * 4 + r;
          O[(size_t)row * 512 + jl] = (f16_t)(acc[i][j][r] + bias);
        }
    }
  } else {
    __syncthreads();
    f16_t* vtl = (f16_t*)smem;          // [128][136] f16 = 34816 B
    #pragma unroll
    for (int j = 0; j < 4; ++j) {
      const int jj = wc * 64 + j * 16 + l15;
      const float bias = bv[jb + jj];
      #pragma unroll
      for (int i = 0; i < 4; ++i)
        #pragma unroll
        for (int r = 0; r < 4; ++r) {
          const int ii = wr * 64 + i * 16 + lg * 4 + r;
          vtl[jj * 136 + ii] = (f16_t)(acc[i][j][r] + bias);
        }
    }
    __syncthreads();
    const int dv = tid >> 1, hf = tid & 1;
    const int bat = rowbase >> 11, n0 = rowbase & 2047;
    f16_t* __restrict__ dst =
        &Vt[((size_t)bat * 512 + jb + dv) * 2048 + n0 + hf * 64];
    const f16_t* src = &vtl[dv * 136 + hf * 64];
    #pragma unroll
    for (int s = 0; s < 8; ++s)
      *(f16x8*)&dst[s * 8] = *(const f16x8*)&src[s * 8];
  }
}

// ---------------------------------------------------------------------------
// S = Q K^T (fp32 out) + encoded row-max atomics.  flat grid 2048.
// decode: bat = wg>>8 (one batch per XCD), mt = (wg>>4)&15, nt = wg&15.
// ---------------------------------------------------------------------------
__global__ __launch_bounds__(256, 2) void k_qk(const f16_t* __restrict__ Q,
                                               const f16_t* __restrict__ K,
                                               float* __restrict__ S,
                                               unsigned int* __restrict__ mEnc)
{
  __shared__ __align__(16) f16_t A[128 * 64];
  __shared__ __align__(16) f16_t Bt[128 * 64];

  const int wg = xcd_swz(blockIdx.x, 2048);
  const int bat = wg >> 8, mt = (wg >> 4) & 15, nt = wg & 15;
  const int tid = threadIdx.x, lane = tid & 63, wave = tid >> 6;
  const int wr = wave >> 1, wc = wave & 1, l15 = lane & 15, lg = lane >> 4;

  f32x4 acc[4][4] = {};
  const f16_t* Abase = Q + ((size_t)bat * 2048 + mt * 128) * 512;
  const f16_t* Bbase = K + ((size_t)bat * 2048 + nt * 128) * 512;

  for (int kb = 0; kb < 512; kb += 64) {
    __syncthreads();
    stage_tile(A, Abase + kb, 512, wave, lane);
    stage_tile(Bt, Bbase + kb, 512, wave, lane);
    __syncthreads();
    #pragma unroll
    for (int h = 0; h < 2; ++h) {
      const int slot0 = h * 4 + lg;
      f16x8 af[4], bf[4];
      #pragma unroll
      for (int g = 0; g < 4; ++g) {
        af[g] = lds_frag(A, wr * 64 + g * 16 + l15, slot0);
        bf[g] = lds_frag(Bt, wc * 64 + g * 16 + l15, slot0);
      }
      #pragma unroll
      for (int i = 0; i < 4; ++i)
        #pragma unroll
        for (int j = 0; j < 4; ++j)
          acc[i][j] = mfma_h(af[i], bf[j], acc[i][j]);
    }
  }

  #pragma unroll
  for (int i = 0; i < 4; ++i)
    #pragma unroll
    for (int r = 0; r < 4; ++r) {
      const int ii = mt * 128 + wr * 64 + i * 16 + lg * 4 + r;
      // row-max over this lane's 4 cols, then over the 16-lane l15 group
      float mv = fmaxf(fmaxf(acc[i][0][r], acc[i][1][r]),
                       fmaxf(acc[i][2][r], acc[i][3][r]));
      mv = fmaxf(mv, __shfl_xor(mv, 1));
      mv = fmaxf(mv, __shfl_xor(mv, 2));
      mv = fmaxf(mv, __shfl_xor(mv, 4));
      mv = fmaxf(mv, __shfl_xor(mv, 8));
      if (l15 == 0)
        atomicMax(&mEnc[(size_t)bat * 2048 + ii], fenc(mv));
      #pragma unroll
      for (int j = 0; j < 4; ++j) {
        const int jj = nt * 128 + wc * 64 + j * 16 + l15;
        S[((size_t)bat * 2048 + ii) * 2048 + jj] = acc[i][j][r];
      }
    }
}

// ---------------------------------------------------------------------------
// out = (exp(S - m) @ V) * sqrt(512)/l.  flat grid 512.
// decode: bat = wg>>6 (one batch per XCD), mt = (wg>>2)&15, nt = wg&3.
// A tile reg-staged: fp32 S -> exp -> f16 into swizzled LDS; l accumulated.
// ---------------------------------------------------------------------------
__global__ __launch_bounds__(256, 2) void k_pv(const float* __restrict__ S,
                                               const f16_t* __restrict__ Vt,
                                               const unsigned int* __restrict__ mEnc,
                                               float* __restrict__ out)
{
  __shared__ __align__(16) f16_t A[128 * 64];
  __shared__ __align__(16) f16_t Bv[128 * 64];

  const int wg = xcd_swz(blockIdx.x, 512);
  const int bat = wg >> 6, mt = (wg >> 2) & 15, nt = wg & 3;
  const int tid = threadIdx.x, lane = tid & 63, wave = tid >> 6;
  const int wr = wave >> 1, wc = wave & 1, l15 = lane & 15, lg = lane >> 4;

  const int r_stage = tid >> 1;          // staging row 0..127
  const int half = tid & 1;              // col half (32 fp32 each)
  const float mrow = fdec(mEnc[(size_t)bat * 2048 + mt * 128 + r_stage]);
  const float* __restrict__ srow =
      S + ((size_t)bat * 2048 + mt * 128 + r_stage) * 2048 + half * 32;
  const f16_t* Bbase = Vt + ((size_t)bat * 512 + nt * 128) * 2048;

  f32x4 acc[4][4] = {};
  float l_part = 0.f;

  for (int kb = 0; kb < 2048; kb += 64) {
    __syncthreads();
    stage_tile(Bv, Bbase + kb, 2048, wave, lane);   // async global->LDS
    // reg-stage A: fp32 -> exp -> f16, swizzled ds_write, accumulate l
    #pragma unroll
    for (int s4 = 0; s4 < 4; ++s4) {
      const float4 a = *(const float4*)&srow[kb + s4 * 8];
      const float4 b = *(const float4*)&srow[kb + s4 * 8 + 4];
      float e[8] = {a.x, a.y, a.z, a.w, b.x, b.y, b.z, b.w};
      f16x8 p;
      #pragma unroll
      for (int j = 0; j < 8; ++j) {
        const float ev = __expf(e[j] - mrow);
        l_part += ev;
        p[j] = (f16_t)ev;
      }
      const int slot = half * 4 + s4;
      *(f16x8*)&A[r_stage * 64 + ((slot ^ (r_stage & 7)) << 3)] = p;
    }
    __syncthreads();
    #pragma unroll
    for (int h = 0; h < 2; ++h) {
      const int slot0 = h * 4 + lg;
      f16x8 af[4], bf[4];
      #pragma unroll
      for (int g = 0; g < 4; ++g) {
        af[g] = lds_frag(A, wr * 64 + g * 16 + l15, slot0);
        bf[g] = lds_frag(Bv, wc * 64 + g * 16 + l15, slot0);
      }
      #pragma unroll
      for (int i = 0; i < 4; ++i)
        #pragma unroll
        for (int j = 0; j < 4; ++j)
          acc[i][j] = mfma_h(af[i], bf[j], acc[i][j]);
    }
  }

  // row-sum reduction: l[row] = l_part(half 0) + l_part(half 1)
  __syncthreads();
  float* lred = (float*)A;               // [128][2] overlays A
  lred[r_stage * 2 + half] = l_part;
  __syncthreads();

  #pragma unroll
  for (int i = 0; i < 4; ++i)
    #pragma unroll
    for (int r = 0; r < 4; ++r) {
      const int il = wr * 64 + i * 16 + lg * 4 + r;
      const float l = lred[il * 2] + lred[il * 2 + 1];
      const float sc = 22.62741699796952f / l;     // sqrt(512)/l
      const int ii = mt * 128 + il;
      #pragma unroll
      for (int j = 0; j < 4; ++j) {
        const int dv = nt * 128 + wc * 64 + j * 16 + l15;
        out[((size_t)bat * 2048 + ii) * 512 + dv] = acc[i][j][r] * sc;
      }
    }
}

// ---------------------------------------------------------------------------
extern "C" void kernel_launch(void* const* d_in, const int* in_sizes, int n_in,
                              void* d_out, int out_size, void* d_ws, size_t ws_size,
                              hipStream_t stream) {
  const float* x  = (const float*)d_in[0];
  const float* Wq = (const float*)d_in[1];
  const float* bq = (const float*)d_in[2];
  const float* Wk = (const float*)d_in[3];
  const float* bk = (const float*)d_in[4];
  const float* Wv = (const float*)d_in[5];
  const float* bv = (const float*)d_in[6];
  float* out = (float*)d_out;

  char* ws = (char*)d_ws;
  f16_t* x16 = (f16_t*)(ws + 0);
  f16_t* Q   = (f16_t*)(ws + 16777216);
  f16_t* K   = (f16_t*)(ws + 33554432);
  f16_t* Vt  = (f16_t*)(ws + 50331648);
  float* S   = (float*)(ws + 67108864);
  f16_t* Wt  = (f16_t*)(ws + 201326592);
  unsigned int* mEnc = (unsigned int*)(ws + 202899456);

  hipMemsetAsync(mEnc, 0, 65536, stream);  // encoded -inf sentinel
  k_conv_x<<<4096, 256, 0, stream>>>(x, x16);
  k_conv_w<<<dim3(8, 8, 3), 256, 0, stream>>>(Wq, Wk, Wv, Wt);
  k_proj<<<1536, 256, 0, stream>>>(x16, Wt, bq, bk, bv, Q, K, Vt);
  k_qk<<<2048, 256, 0, stream>>>(Q, K, S, mEnc);
  k_pv<<<512, 256, 0, stream>>>(S, Vt, mEnc, out);
}

// Round 4
// 160.082 us; speedup vs baseline: 2.3568x; 1.1556x over previous
//
#include <hip/hip_runtime.h>
#include <stdint.h>
#include <stddef.h>

// ---------------------------------------------------------------------------
// out = softmax(x Wq+bq @ (x Wk+bk)^T) * sqrt(512) @ (x Wv+bv)
// B=8, N=2048, D=DK=DV=512, fp32 I/O.
// Round 4: k_pv restructured -- exp once per (q,kv) (shared P_lds), square
// 64x64 wave tiles (MFMA:ds_read ratio of the proven GEMMs), S streamed
// exactly once from HBM. conv/proj/qk unchanged from round 3.
// ws layout (B): x16 0, Q 16777216, K 33554432, Vt 50331648,
//   S 67108864 (134217728), Wt 201326592 (1572864), mEnc 202899456 (65536).
//   total 202964992.
// ---------------------------------------------------------------------------

typedef _Float16 f16_t;
typedef _Float16 f16x8 __attribute__((ext_vector_type(8)));
typedef float    f32x4 __attribute__((ext_vector_type(4)));

__device__ __forceinline__ f32x4 mfma_h(f16x8 a, f16x8 b, f32x4 c) {
  // D frag: col = lane&15, row = (lane>>4)*4 + reg
  return __builtin_amdgcn_mfma_f32_16x16x32_f16(a, b, c, 0, 0, 0);
}

__device__ __forceinline__ void gl_lds16(const void* g, void* lds) {
  __builtin_amdgcn_global_load_lds(
      (const __attribute__((address_space(1))) unsigned int*)g,
      (__attribute__((address_space(3))) unsigned int*)lds, 16, 0, 0);
}

// Stage a [128][64] f16 tile (16 KB) from row-major global via global_load_lds.
// Linear LDS dest; source pre-swizzled: phys slot s of row r holds logical
// slot s^(r&7) (16B slots, 8 per 128B row).  4-wave cooperative.
__device__ __forceinline__ void stage_tile(f16_t* lds, const f16_t* g,
                                           size_t gstride, int wave, int lane) {
  const int l8 = lane >> 3;
  const int lslot = (lane & 7) ^ l8;
  #pragma unroll
  for (int c = 0; c < 4; ++c) {
    const int chunk = wave * 4 + c;
    const int row = chunk * 8 + l8;
    gl_lds16(g + (size_t)row * gstride + lslot * 8, lds + chunk * 512);
  }
}

// Swizzled fragment read: logical (row R, 8 elems at col slot*8)
__device__ __forceinline__ f16x8 lds_frag(const f16_t* buf, int R, int slot) {
  return *(const f16x8*)&buf[R * 64 + (((slot ^ (R & 7)) & 7) << 3)];
}

// monotonic float<->uint encoding for atomicMax (memset-0 == -huge sentinel)
__device__ __forceinline__ unsigned int fenc(float f) {
  unsigned int u = __float_as_uint(f);
  return (u & 0x80000000u) ? ~u : (u | 0x80000000u);
}
__device__ __forceinline__ float fdec(unsigned int e) {
  unsigned int u = (e & 0x80000000u) ? (e & 0x7fffffffu) : ~e;
  return __uint_as_float(u);
}

// XCD-chunked work remap (requires nwg % 8 == 0)
__device__ __forceinline__ int xcd_swz(int id, int nwg) {
  return (id & 7) * (nwg >> 3) + (id >> 3);
}

// ---------------------------------------------------------------------------
__global__ __launch_bounds__(256) void k_conv_x(const float* __restrict__ x,
                                                f16_t* __restrict__ x16) {
  const int i = (blockIdx.x * 256 + threadIdx.x) * 8;
  const float4 a = *(const float4*)&x[i];
  const float4 b = *(const float4*)&x[i + 4];
  float v[8] = {a.x, a.y, a.z, a.w, b.x, b.y, b.z, b.w};
  f16x8 h;
  #pragma unroll
  for (int j = 0; j < 8; ++j) h[j] = (f16_t)v[j];
  *(f16x8*)&x16[i] = h;
}

// transpose+convert W -> Wt[p][n][k] f16
__global__ __launch_bounds__(256) void k_conv_w(const float* __restrict__ Wq,
                                                const float* __restrict__ Wk,
                                                const float* __restrict__ Wv,
                                                f16_t* __restrict__ Wt) {
  __shared__ float t[64][65];
  const int p = blockIdx.z;
  const float* __restrict__ W = (p == 0) ? Wq : (p == 1) ? Wk : Wv;
  const int n0 = blockIdx.x * 64, k0 = blockIdx.y * 64;
  const int tx = threadIdx.x & 63, ty = threadIdx.x >> 6;
  #pragma unroll
  for (int j = 0; j < 16; ++j)
    t[ty * 16 + j][tx] = W[(size_t)(k0 + ty * 16 + j) * 512 + n0 + tx];
  __syncthreads();
  #pragma unroll
  for (int j = 0; j < 16; ++j) {
    const int nl = ty * 16 + j;
    Wt[(size_t)p * 262144 + (size_t)(n0 + nl) * 512 + k0 + tx] =
        (f16_t)t[tx][nl];
  }
}

// ---------------------------------------------------------------------------
// Projection: flat grid 1536 (xcd-swizzled -> mt*12+jt).  Single fp16 MFMA.
// panels 0-3 Q, 4-7 K, 8-11 V (V transposed to Vt[b][dv][n]).
// ---------------------------------------------------------------------------
__global__ __launch_bounds__(256, 2) void k_proj(
    const f16_t* __restrict__ x16, const f16_t* __restrict__ Wt,
    const float* __restrict__ bq, const float* __restrict__ bk,
    const float* __restrict__ bv,
    f16_t* __restrict__ Q, f16_t* __restrict__ K, f16_t* __restrict__ Vt)
{
  __shared__ __align__(16) unsigned char smem[34816];  // A,B tiles / vtl
  f16_t* A = (f16_t*)smem;
  f16_t* B = (f16_t*)(smem + 16384);

  const int wg = xcd_swz(blockIdx.x, 1536);
  const int mt = wg / 12, jt = wg % 12;
  const int which = jt >> 2;            // 0=Q 1=K 2=V
  const int jb = (jt & 3) * 128;

  const int tid = threadIdx.x, lane = tid & 63, wave = tid >> 6;
  const int wr = wave >> 1, wc = wave & 1, l15 = lane & 15, lg = lane >> 4;
  const int rowbase = mt * 128;

  const f16_t* Wbase = Wt + (size_t)which * 262144 + (size_t)jb * 512;

  f32x4 acc[4][4] = {};

  for (int kb = 0; kb < 512; kb += 64) {
    __syncthreads();
    stage_tile(A, x16 + (size_t)rowbase * 512 + kb, 512, wave, lane);
    stage_tile(B, Wbase + kb, 512, wave, lane);
    __syncthreads();
    #pragma unroll
    for (int h = 0; h < 2; ++h) {
      const int slot0 = h * 4 + lg;
      f16x8 af[4], bf[4];
      #pragma unroll
      for (int g = 0; g < 4; ++g) {
        af[g] = lds_frag(A, wr * 64 + g * 16 + l15, slot0);
        bf[g] = lds_frag(B, wc * 64 + g * 16 + l15, slot0);
      }
      #pragma unroll
      for (int i = 0; i < 4; ++i)
        #pragma unroll
        for (int j = 0; j < 4; ++j)
          acc[i][j] = mfma_h(af[i], bf[j], acc[i][j]);
    }
  }

  if (which != 2) {
    f16_t* __restrict__ O = (which == 0) ? Q : K;
    const float* __restrict__ bb = (which == 0) ? bq : bk;
    #pragma unroll
    for (int j = 0; j < 4; ++j) {
      const int jl = jb + wc * 64 + j * 16 + l15;
      const float bias = bb[jl];
      #pragma unroll
      for (int i = 0; i < 4; ++i)
        #pragma unroll
        for (int r = 0; r < 4; ++r) {
          const int row = rowbase + wr * 64 + i * 16 + lg * 4 + r;
          O[(size_t)row * 512 + jl] = (f16_t)(acc[i][j][r] + bias);
        }
    }
  } else {
    __syncthreads();
    f16_t* vtl = (f16_t*)smem;          // [128][136] f16 = 34816 B
    #pragma unroll
    for (int j = 0; j < 4; ++j) {
      const int jj = wc * 64 + j * 16 + l15;
      const float bias = bv[jb + jj];
      #pragma unroll
      for (int i = 0; i < 4; ++i)
        #pragma unroll
        for (int r = 0; r < 4; ++r) {
          const int ii = wr * 64 + i * 16 + lg * 4 + r;
          vtl[jj * 136 + ii] = (f16_t)(acc[i][j][r] + bias);
        }
    }
    __syncthreads();
    const int dv = tid >> 1, hf = tid & 1;
    const int bat = rowbase >> 11, n0 = rowbase & 2047;
    f16_t* __restrict__ dst =
        &Vt[((size_t)bat * 512 + jb + dv) * 2048 + n0 + hf * 64];
    const f16_t* src = &vtl[dv * 136 + hf * 64];
    #pragma unroll
    for (int s = 0; s < 8; ++s)
      *(f16x8*)&dst[s * 8] = *(const f16x8*)&src[s * 8];
  }
}

// ---------------------------------------------------------------------------
// S = Q K^T (fp32 out) + encoded row-max atomics.  flat grid 2048.
// decode: bat = wg>>8 (one batch per XCD), mt = (wg>>4)&15, nt = wg&15.
// ---------------------------------------------------------------------------
__global__ __launch_bounds__(256, 2) void k_qk(const f16_t* __restrict__ Q,
                                               const f16_t* __restrict__ K,
                                               float* __restrict__ S,
                                               unsigned int* __restrict__ mEnc)
{
  __shared__ __align__(16) f16_t A[128 * 64];
  __shared__ __align__(16) f16_t Bt[128 * 64];

  const int wg = xcd_swz(blockIdx.x, 2048);
  const int bat = wg >> 8, mt = (wg >> 4) & 15, nt = wg & 15;
  const int tid = threadIdx.x, lane = tid & 63, wave = tid >> 6;
  const int wr = wave >> 1, wc = wave & 1, l15 = lane & 15, lg = lane >> 4;

  f32x4 acc[4][4] = {};
  const f16_t* Abase = Q + ((size_t)bat * 2048 + mt * 128) * 512;
  const f16_t* Bbase = K + ((size_t)bat * 2048 + nt * 128) * 512;

  for (int kb = 0; kb < 512; kb += 64) {
    __syncthreads();
    stage_tile(A, Abase + kb, 512, wave, lane);
    stage_tile(Bt, Bbase + kb, 512, wave, lane);
    __syncthreads();
    #pragma unroll
    for (int h = 0; h < 2; ++h) {
      const int slot0 = h * 4 + lg;
      f16x8 af[4], bf[4];
      #pragma unroll
      for (int g = 0; g < 4; ++g) {
        af[g] = lds_frag(A, wr * 64 + g * 16 + l15, slot0);
        bf[g] = lds_frag(Bt, wc * 64 + g * 16 + l15, slot0);
      }
      #pragma unroll
      for (int i = 0; i < 4; ++i)
        #pragma unroll
        for (int j = 0; j < 4; ++j)
          acc[i][j] = mfma_h(af[i], bf[j], acc[i][j]);
    }
  }

  #pragma unroll
  for (int i = 0; i < 4; ++i)
    #pragma unroll
    for (int r = 0; r < 4; ++r) {
      const int ii = mt * 128 + wr * 64 + i * 16 + lg * 4 + r;
      float mv = fmaxf(fmaxf(acc[i][0][r], acc[i][1][r]),
                       fmaxf(acc[i][2][r], acc[i][3][r]));
      mv = fmaxf(mv, __shfl_xor(mv, 1));
      mv = fmaxf(mv, __shfl_xor(mv, 2));
      mv = fmaxf(mv, __shfl_xor(mv, 4));
      mv = fmaxf(mv, __shfl_xor(mv, 8));
      if (l15 == 0)
        atomicMax(&mEnc[(size_t)bat * 2048 + ii], fenc(mv));
      #pragma unroll
      for (int j = 0; j < 4; ++j) {
        const int jj = nt * 128 + wc * 64 + j * 16 + l15;
        S[((size_t)bat * 2048 + ii) * 2048 + jj] = acc[i][j][r];
      }
    }
}

// ---------------------------------------------------------------------------
// out = (exp(S - m) @ V) * sqrt(512)/l.  flat grid 512 = bat(8, =XCD) x
// qt(32 tiles of 64 q) x dvh(2 halves of 256 dv).  4 waves, each 64q x 64dv.
// exp computed ONCE per (q,kv) into shared P_lds; S streamed once from HBM.
// ---------------------------------------------------------------------------
__global__ __launch_bounds__(256, 2) void k_pv2(const float* __restrict__ S,
                                                const f16_t* __restrict__ Vt,
                                                const unsigned int* __restrict__ mEnc,
                                                float* __restrict__ out)
{
  __shared__ __align__(16) f16_t P[64 * 64];      // [q][kv] swizzled, 8 KB
  __shared__ __align__(16) f16_t Vl[256 * 64];    // [dv][kv] swizzled, 32 KB
  __shared__ float lred[64][4];

  const int id = blockIdx.x;
  const int bat = id & 7, qt = (id >> 3) & 31, dvh = id >> 8;
  const int tid = threadIdx.x, lane = tid & 63, wave = tid >> 6;
  const int l15 = lane & 15, lg = lane >> 4;

  const int qs = tid >> 2;           // staging q row 0..63
  const int cq = tid & 3;            // quarter of the 64-kv step
  const float mrow = fdec(mEnc[bat * 2048 + qt * 64 + qs]);
  const float* __restrict__ srow =
      S + ((size_t)bat * 2048 + qt * 64 + qs) * 2048;
  const f16_t* Vbase = Vt + ((size_t)bat * 512 + dvh * 256) * 2048;

  f32x4 acc[4][4] = {};
  float l_part = 0.f;

  for (int kb = 0; kb < 2048; kb += 64) {
    __syncthreads();
    stage_tile(Vl, Vbase + kb, 2048, wave, lane);
    stage_tile(Vl + 128 * 64, Vbase + (size_t)128 * 2048 + kb, 2048, wave, lane);
    // reg-stage P: 16 fp32 -> exp -> f16, two swizzled b128 writes
    #pragma unroll
    for (int s2 = 0; s2 < 2; ++s2) {
      const int kv0 = cq * 16 + s2 * 8;
      const float4 a = *(const float4*)&srow[kb + kv0];
      const float4 b = *(const float4*)&srow[kb + kv0 + 4];
      float e[8] = {a.x, a.y, a.z, a.w, b.x, b.y, b.z, b.w};
      f16x8 p;
      #pragma unroll
      for (int j = 0; j < 8; ++j) {
        const float ev = __expf(e[j] - mrow);
        l_part += ev;
        p[j] = (f16_t)ev;
      }
      const int slot = cq * 2 + s2;
      *(f16x8*)&P[qs * 64 + ((slot ^ (qs & 7)) << 3)] = p;
    }
    __syncthreads();
    #pragma unroll
    for (int ks = 0; ks < 2; ++ks) {
      const int slot0 = ks * 4 + lg;
      f16x8 af[4], bf[4];
      #pragma unroll
      for (int g = 0; g < 4; ++g) {
        af[g] = lds_frag(P, g * 16 + l15, slot0);
        bf[g] = lds_frag(Vl, wave * 64 + g * 16 + l15, slot0);
      }
      #pragma unroll
      for (int i = 0; i < 4; ++i)
        #pragma unroll
        for (int j = 0; j < 4; ++j)
          acc[i][j] = mfma_h(af[i], bf[j], acc[i][j]);
    }
  }

  __syncthreads();
  lred[qs][cq] = l_part;
  __syncthreads();

  #pragma unroll
  for (int i = 0; i < 4; ++i)
    #pragma unroll
    for (int r = 0; r < 4; ++r) {
      const int ql = i * 16 + lg * 4 + r;
      const float l = lred[ql][0] + lred[ql][1] + lred[ql][2] + lred[ql][3];
      const float sc = 22.62741699796952f / l;   // sqrt(512)/l
      const size_t orow = ((size_t)bat * 2048 + qt * 64 + ql) * 512;
      #pragma unroll
      for (int j = 0; j < 4; ++j) {
        const int dv = dvh * 256 + wave * 64 + j * 16 + l15;
        out[orow + dv] = acc[i][j][r] * sc;
      }
    }
}

// ---------------------------------------------------------------------------
extern "C" void kernel_launch(void* const* d_in, const int* in_sizes, int n_in,
                              void* d_out, int out_size, void* d_ws, size_t ws_size,
                              hipStream_t stream) {
  const float* x  = (const float*)d_in[0];
  const float* Wq = (const float*)d_in[1];
  const float* bq = (const float*)d_in[2];
  const float* Wk = (const float*)d_in[3];
  const float* bk = (const float*)d_in[4];
  const float* Wv = (const float*)d_in[5];
  const float* bv = (const float*)d_in[6];
  float* out = (float*)d_out;

  char* ws = (char*)d_ws;
  f16_t* x16 = (f16_t*)(ws + 0);
  f16_t* Q   = (f16_t*)(ws + 16777216);
  f16_t* K   = (f16_t*)(ws + 33554432);
  f16_t* Vt  = (f16_t*)(ws + 50331648);
  float* S   = (float*)(ws + 67108864);
  f16_t* Wt  = (f16_t*)(ws + 201326592);
  unsigned int* mEnc = (unsigned int*)(ws + 202899456);

  hipMemsetAsync(mEnc, 0, 65536, stream);  // encoded -inf sentinel
  k_conv_x<<<4096, 256, 0, stream>>>(x, x16);
  k_conv_w<<<dim3(8, 8, 3), 256, 0, stream>>>(Wq, Wk, Wv, Wt);
  k_proj<<<1536, 256, 0, stream>>>(x16, Wt, bq, bk, bv, Q, K, Vt);
  k_qk<<<2048, 256, 0, stream>>>(Q, K, S, mEnc);
  k_pv2<<<512, 256, 0, stream>>>(S, Vt, mEnc, out);
}